// Round 1
// baseline (4637.288 us; speedup 1.0000x reference)
//
#include <hip/hip_runtime.h>

#define N_VEC 131072
#define DIM 256
#define KCODES 512
#define NUM_VQ 4

constexpr float BETA = 0.2f;
constexpr int BM = 64;        // rows per block
constexpr int BD = 16;        // dims per LDS chunk
constexpr int NTHREADS = 256;
constexpr int NBLOCKS = N_VEC / BM;   // 2048 per stage

// ---------------- codebook norms ----------------
__global__ void norms_kernel(const float* __restrict__ cb, float* __restrict__ norms) {
    int row = blockIdx.x * 4 + (threadIdx.x >> 6);     // one wave per row
    int lane = threadIdx.x & 63;
    const float* r = cb + (size_t)row * DIM;
    float4 v = *(const float4*)(r + lane * 4);
    float s = v.x * v.x + v.y * v.y + v.z * v.z + v.w * v.w;
    #pragma unroll
    for (int off = 32; off; off >>= 1) s += __shfl_down(s, off);
    if (lane == 0) norms[row] = s;
}

// ---------------- one residual-VQ stage ----------------
// xin: residual input rows (row stride xin_stride floats). qout: quantized output
// column base (row stride 1024). resout: residual output (may be null / alias xin).
__global__ __launch_bounds__(NTHREADS)
void vq_stage_kernel(const float* xin, int xin_stride,
                     const float* __restrict__ cb,     // [512][256] this stage
                     const float* __restrict__ norms,  // [512]
                     float* qout,
                     float* resout,
                     float* __restrict__ sq_partials,  // [NBLOCKS]
                     int* __restrict__ hist,           // [512]
                     const int* __restrict__ emap,     // stage0 only
                     float* __restrict__ logits)       // stage0 only
{
    __shared__ float As[BM][20];      // pad to 20 floats: conflict-free
    __shared__ float Bs[256][20];
    __shared__ float ns[KCODES];
    __shared__ int   sidx[BM];
    __shared__ float red[4];

    const int tid = threadIdx.x;
    const int tk  = tid & 15;         // code group
    const int tmg = tid >> 4;         // row group 0..15
    const long row0 = (long)blockIdx.x * BM;

    ns[tid]       = norms[tid];
    ns[tid + 256] = norms[tid + 256];

    float minv[4];
    int   mini[4];
    #pragma unroll
    for (int m = 0; m < 4; ++m) { minv[m] = 3.4e38f; mini[m] = 0; }

    const int srow = tid >> 2;        // staging row 0..63
    const int sf   = tid & 3;         // staging float4 slot

    for (int half = 0; half < 2; ++half) {
        float acc[4][16];
        #pragma unroll
        for (int m = 0; m < 4; ++m)
            #pragma unroll
            for (int kk = 0; kk < 16; ++kk) acc[m][kk] = 0.f;

        const float* cbh = cb + (size_t)half * 256 * DIM;

        for (int dc = 0; dc < DIM; dc += BD) {
            __syncthreads();
            // stage A: 64 rows x 16 floats
            {
                const float* src = xin + (row0 + srow) * (long)xin_stride + dc + sf * 4;
                float4 v = *(const float4*)src;
                *(float4*)(&As[srow][sf * 4]) = v;
            }
            // stage B: 256 codes x 16 floats
            #pragma unroll
            for (int r = 0; r < 4; ++r) {
                int kr = srow + 64 * r;
                const float* src = cbh + (size_t)kr * DIM + dc + sf * 4;
                float4 v = *(const float4*)src;
                *(float4*)(&Bs[kr][sf * 4]) = v;
            }
            __syncthreads();
            // compute: acc[m][kk] += A[row][*] . B[code][*]
            #pragma unroll
            for (int e = 0; e < 4; ++e) {
                float4 av[4];
                #pragma unroll
                for (int m = 0; m < 4; ++m)
                    av[m] = *(const float4*)(&As[4 * tmg + m][e * 4]);
                #pragma unroll
                for (int kk = 0; kk < 16; ++kk) {
                    float4 bv = *(const float4*)(&Bs[tk + 16 * kk][e * 4]);
                    #pragma unroll
                    for (int m = 0; m < 4; ++m) {
                        acc[m][kk] += av[m].x * bv.x + av[m].y * bv.y
                                    + av[m].z * bv.z + av[m].w * bv.w;
                    }
                }
            }
        }
        // fold this half into running min
        #pragma unroll
        for (int m = 0; m < 4; ++m) {
            #pragma unroll
            for (int kk = 0; kk < 16; ++kk) {
                int k = half * 256 + tk + 16 * kk;
                float s = ns[k] - 2.f * acc[m][kk];
                if (s < minv[m] || (s == minv[m] && k < mini[m])) { minv[m] = s; mini[m] = k; }
            }
        }
    }

    // reduce argmin across the 16 tk lanes (xor masks stay inside the group)
    #pragma unroll
    for (int m = 0; m < 4; ++m) {
        #pragma unroll
        for (int off = 1; off < 16; off <<= 1) {
            float ov = __shfl_xor(minv[m], off);
            int   oi = __shfl_xor(mini[m], off);
            if (ov < minv[m] || (ov == minv[m] && oi < mini[m])) { minv[m] = ov; mini[m] = oi; }
        }
        if (tk == 0) sidx[4 * tmg + m] = mini[m];
    }
    __syncthreads();

    // -------- epilogue: gather, ST-rounding, residual, loss --------
    const int lrow = tid >> 2;
    const int k    = sidx[lrow];
    const long grow = row0 + lrow;
    const float* cbr = cb + (size_t)k * DIM;
    const float* xr  = xin + grow * (long)xin_stride;
    float* qr = qout + grow * 1024;
    float* rr = resout ? resout + grow * 1024 : nullptr;
    float lsq = 0.f;
    #pragma unroll
    for (int e = 0; e < 16; ++e) {
        int f = (tid & 3) + 4 * e;     // float4 index 0..63, coalesced in 4-lane groups
        float4 x = *(const float4*)(xr + f * 4);
        float4 c = *(const float4*)(cbr + f * 4);
        float4 q;
        q.x = x.x + (c.x - x.x); q.y = x.y + (c.y - x.y);
        q.z = x.z + (c.z - x.z); q.w = x.w + (c.w - x.w);
        float4 rv;
        rv.x = x.x - q.x; rv.y = x.y - q.y; rv.z = x.z - q.z; rv.w = x.w - q.w;
        *(float4*)(qr + f * 4) = q;
        if (rr) *(float4*)(rr + f * 4) = rv;
        lsq += rv.x * rv.x + rv.y * rv.y + rv.z * rv.z + rv.w * rv.w;
    }
    // block-deterministic sq reduction
    #pragma unroll
    for (int off = 32; off; off >>= 1) lsq += __shfl_down(lsq, off);
    if ((tid & 63) == 0) red[tid >> 6] = lsq;
    __syncthreads();
    if (tid == 0) sq_partials[blockIdx.x] = red[0] + red[1] + red[2] + red[3];

    if (tid < 64) atomicAdd(&hist[sidx[tid]], 1);
    if (emap && tid < 64) logits[row0 + tid] = (float)emap[sidx[tid]];
}

// ---------------- finalize: loss + perplexities ----------------
__global__ void finalize_kernel(const float* __restrict__ sq_partials,  // [4*NBLOCKS]
                                const int* __restrict__ hist,           // [4*512]
                                float* __restrict__ loss_out,
                                float* __restrict__ perp_out)
{
    __shared__ float sred[8];
    int tid = threadIdx.x;  // 512 threads
    float s = 0.f;
    for (int i = tid; i < NUM_VQ * NBLOCKS; i += 512) s += sq_partials[i];
    #pragma unroll
    for (int off = 32; off; off >>= 1) s += __shfl_down(s, off);
    if ((tid & 63) == 0) sred[tid >> 6] = s;
    __syncthreads();
    if (tid == 0) {
        float t = 0.f;
        for (int i = 0; i < 8; ++i) t += sred[i];
        *loss_out = (1.f + BETA) * t / ((float)N_VEC * (float)DIM);
    }
    for (int st = 0; st < NUM_VQ; ++st) {
        __syncthreads();
        float e = (float)hist[st * 512 + tid] * (1.f / (float)N_VEC);
        float term = e * logf(e + 1e-10f);
        #pragma unroll
        for (int off = 32; off; off >>= 1) term += __shfl_down(term, off);
        if ((tid & 63) == 0) sred[tid >> 6] = term;
        __syncthreads();
        if (tid == 0) {
            float t = 0.f;
            for (int i = 0; i < 8; ++i) t += sred[i];
            perp_out[st] = expf(-t);
        }
    }
}

extern "C" void kernel_launch(void* const* d_in, const int* in_sizes, int n_in,
                              void* d_out, int out_size, void* d_ws, size_t ws_size,
                              hipStream_t stream) {
    const float* x    = (const float*)d_in[0];
    const float* cbs  = (const float*)d_in[1];
    const int*   emap = (const int*)d_in[2];
    float* out = (float*)d_out;

    const size_t QSZ = (size_t)N_VEC * (NUM_VQ * DIM);   // 134217728
    float* loss_out = out + QSZ;
    float* logits   = out + QSZ + 1;
    float* perp     = out + QSZ + 1 + N_VEC;

    // workspace: [0..4*2048) sq partials (f32) | [..+4*512) hist (i32) | [..+2048) norms (f32)
    float* sq_partials = (float*)d_ws;
    int*   hist        = (int*)(sq_partials + NUM_VQ * NBLOCKS);
    float* norms       = (float*)(hist + NUM_VQ * KCODES);

    hipMemsetAsync(d_ws, 0, (size_t)(NUM_VQ * NBLOCKS + NUM_VQ * KCODES) * 4, stream);

    norms_kernel<<<NUM_VQ * KCODES / 4, 256, 0, stream>>>(cbs, norms);

    // residual lives in the stage-3 output column (overwritten last by stage 3's q)
    float* resid = out + 3 * DIM;   // row stride 1024

    for (int s = 0; s < NUM_VQ; ++s) {
        const float* xin = (s == 0) ? x : resid;
        int xstride      = (s == 0) ? DIM : 1024;
        float* qout      = out + s * DIM;
        float* resout    = (s == NUM_VQ - 1) ? nullptr : resid;
        vq_stage_kernel<<<NBLOCKS, NTHREADS, 0, stream>>>(
            xin, xstride,
            cbs + (size_t)s * KCODES * DIM,
            norms + s * KCODES,
            qout, resout,
            sq_partials + s * NBLOCKS,
            hist + s * KCODES,
            (s == 0) ? emap : nullptr,
            (s == 0) ? logits : nullptr);
    }
    finalize_kernel<<<1, 512, 0, stream>>>(sq_partials, hist, loss_out, perp);
}

// Round 2
// 1169.602 us; speedup vs baseline: 3.9648x; 3.9648x over previous
//
#include <hip/hip_runtime.h>

#define N_VEC 131072
#define DIM 256
#define KCODES 512
#define NUM_VQ 4

constexpr float BETA = 0.2f;
constexpr int BM = 64;
constexpr int NTHREADS = 256;
constexpr int NBLOCKS = N_VEC / BM;   // 2048

typedef short bf16x8 __attribute__((ext_vector_type(8)));
typedef float f32x4  __attribute__((ext_vector_type(4)));

__device__ __forceinline__ unsigned short f2bf(float x) {
    unsigned u = __builtin_bit_cast(unsigned, x);
    u += 0x7FFF + ((u >> 16) & 1);          // round-to-nearest-even
    return (unsigned short)(u >> 16);
}
__device__ __forceinline__ float bf2f(unsigned short h) {
    unsigned u = ((unsigned)h) << 16;
    return __builtin_bit_cast(float, u);
}

#define GLDS16(gp, lp) __builtin_amdgcn_global_load_lds( \
    (const __attribute__((address_space(1))) unsigned int*)(gp), \
    (__attribute__((address_space(3))) unsigned int*)(lp), 16, 0, 0)

// ---------------- codebook norms (exact fp32) ----------------
__global__ void norms_kernel(const float* __restrict__ cb, float* __restrict__ norms) {
    int row = blockIdx.x * 4 + (threadIdx.x >> 6);
    int lane = threadIdx.x & 63;
    const float* r = cb + (size_t)row * DIM;
    float4 v = *(const float4*)(r + lane * 4);
    float s = v.x * v.x + v.y * v.y + v.z * v.z + v.w * v.w;
    #pragma unroll
    for (int off = 32; off; off >>= 1) s += __shfl_down(s, off);
    if (lane == 0) norms[row] = s;
}

// ---------------- codebook -> pre-swizzled bf16 hi/lo chunks ----------------
// Layout: per stage 16 chunks of 32KB: chunks 0-7 = hi plane ks 0..7, 8-15 = lo plane.
// Within a chunk: granule G = col*4 + (k0 ^ ((col>>1)&3)), 16B each (8 bf16, k-contig).
__global__ void bprep_kernel(const float* __restrict__ cb, char* __restrict__ bp) {
    int id = blockIdx.x * 256 + threadIdx.x;   // 131072
    int s   = id >> 15;
    int p   = (id >> 14) & 1;
    int col = (id >> 5) & 511;
    int k8  = id & 31;
    const float* src = cb + (((size_t)s * KCODES + col) * DIM + k8 * 8);
    float4 v0 = *(const float4*)src;
    float4 v1 = *(const float4*)(src + 4);
    float xs[8] = {v0.x, v0.y, v0.z, v0.w, v1.x, v1.y, v1.z, v1.w};
    bf16x8 o;
    #pragma unroll
    for (int i = 0; i < 8; ++i) {
        unsigned short hi = f2bf(xs[i]);
        o[i] = (short)(p ? f2bf(xs[i] - bf2f(hi)) : hi);
    }
    int ks = k8 >> 2, k0 = k8 & 3;
    size_t chunk = (size_t)(s * 2 + p) * 8 + ks;
    int gran = col * 4 + (k0 ^ ((col >> 1) & 3));
    *(bf16x8*)(bp + chunk * 32768 + (size_t)gran * 16) = o;
}

// ---------------- one residual-VQ stage (MFMA) ----------------
__global__ __launch_bounds__(NTHREADS)
void vq_stage_mfma(const float* xin, int xin_stride,
                   const char* __restrict__ bp,     // this stage's 16 chunks
                   const float* __restrict__ cb,    // fp32 codebook this stage
                   const float* __restrict__ norms, // [512]
                   float* qout, float* resout,
                   float* __restrict__ sq_partials,
                   int* __restrict__ hist,
                   const int* __restrict__ emap,
                   float* __restrict__ logits)
{
    __shared__ __align__(16) char Ahi[32768];
    __shared__ __align__(16) char Alo[32768];
    __shared__ __align__(16) char Bb[2][32768];
    __shared__ float ns[KCODES];
    __shared__ float wmin[4][BM];
    __shared__ int   widx[4][BM];
    __shared__ int   sidx[BM];
    __shared__ float red[4];

    const int tid  = threadIdx.x;
    const int w    = tid >> 6;
    const int lane = tid & 63;
    const int l15  = lane & 15;
    const int h16  = lane >> 4;        // 0..3
    const long row0 = (long)blockIdx.x * BM;

    // ---- stage A: 64x256 fp32 -> hi/lo bf16, XOR-swizzled ----
    #pragma unroll
    for (int e = 0; e < 8; ++e) {
        int ga = e * 256 + tid;
        int row = ga >> 5, k8 = ga & 31;
        const float* src = xin + (row0 + row) * (long)xin_stride + k8 * 8;
        float4 v0 = *(const float4*)src;
        float4 v1 = *(const float4*)(src + 4);
        float xs[8] = {v0.x, v0.y, v0.z, v0.w, v1.x, v1.y, v1.z, v1.w};
        bf16x8 h, l;
        #pragma unroll
        for (int i = 0; i < 8; ++i) {
            unsigned short hb = f2bf(xs[i]);
            h[i] = (short)hb;
            l[i] = (short)f2bf(xs[i] - bf2f(hb));
        }
        int off = ((row << 9) + (k8 << 4)) ^ ((row & 7) << 4);
        *(bf16x8*)(Ahi + off) = h;
        *(bf16x8*)(Alo + off) = l;
    }
    ns[tid]       = norms[tid];
    ns[tid + 256] = norms[tid + 256];

    // issue chunk 0 into Bb[0]
    {
        const char* gsrc = bp;                 // chunk 0 (hi, ks=0)
        char* ldst = Bb[0];
        #pragma unroll
        for (int it = 0; it < 8; ++it)
            GLDS16(gsrc + it * 4096 + tid * 16,
                   ldst + it * 4096 + ((tid & 192) << 4));
    }
    __syncthreads();   // drains A ds_writes, ns, and chunk0 (full drain ok once)

    f32x4 acc[4][8];
    #pragma unroll
    for (int t = 0; t < 4; ++t)
        #pragma unroll
        for (int c = 0; c < 8; ++c)
            acc[t][c] = (f32x4){0.f, 0.f, 0.f, 0.f};

    // K' = 768: pass 0 (Ahi,Bhi) j=0..7, pass 1 (Alo,Bhi) j=8..15, pass 2 (Ahi,Blo) j=16..23
    #pragma unroll
    for (int j = 0; j < 24; ++j) {
        __builtin_amdgcn_s_barrier();                 // WAR: buf (j+1)&1 free
        const int jn = (j + 1 < 24) ? j + 1 : 23;     // dummy re-issue at tail
        {
            int chunk = ((jn >= 16) ? 8 : 0) + (jn & 7);
            const char* gsrc = bp + (size_t)chunk * 32768;
            char* ldst = Bb[(j + 1) & 1];
            #pragma unroll
            for (int it = 0; it < 8; ++it)
                GLDS16(gsrc + it * 4096 + tid * 16,
                       ldst + it * 4096 + ((tid & 192) << 4));
        }
        asm volatile("s_waitcnt vmcnt(8)" ::: "memory");  // chunk j resident
        __builtin_amdgcn_s_barrier();

        const char* ap   = ((j >> 3) == 1) ? Alo : Ahi;
        const char* bbuf = Bb[j & 1];
        const int ks = j & 7;

        bf16x8 af[4];
        #pragma unroll
        for (int t = 0; t < 4; ++t) {
            int row = t * 16 + l15;
            int k8 = ks * 4 + h16;
            int off = ((row << 9) + (k8 << 4)) ^ ((row & 7) << 4);
            af[t] = *(const bf16x8*)(ap + off);
        }
        bf16x8 bf[8];
        #pragma unroll
        for (int c = 0; c < 8; ++c) {
            int col = w * 128 + c * 16 + l15;
            int gran = col * 4 + (h16 ^ ((col >> 1) & 3));
            bf[c] = *(const bf16x8*)(bbuf + gran * 16);
        }
        #pragma unroll
        for (int c = 0; c < 8; ++c)
            #pragma unroll
            for (int t = 0; t < 4; ++t)
                acc[t][c] = __builtin_amdgcn_mfma_f32_16x16x32_bf16(af[t], bf[c], acc[t][c], 0, 0, 0);
    }

    // ---- argmin: scores s = ||c||^2 - 2*dot ----
    #pragma unroll
    for (int t = 0; t < 4; ++t) {
        #pragma unroll
        for (int r = 0; r < 4; ++r) {
            float bv = 3.4e38f; int bk = 0;
            #pragma unroll
            for (int c = 0; c < 8; ++c) {
                int col = w * 128 + c * 16 + l15;
                float s = ns[col] - 2.0f * acc[t][c][r];
                if (s < bv || (s == bv && col < bk)) { bv = s; bk = col; }
            }
            #pragma unroll
            for (int m = 1; m < 16; m <<= 1) {
                float ov = __shfl_xor(bv, m);
                int   ok = __shfl_xor(bk, m);
                if (ov < bv || (ov == bv && ok < bk)) { bv = ov; bk = ok; }
            }
            if (l15 == 0) {
                int row = t * 16 + h16 * 4 + r;
                wmin[w][row] = bv; widx[w][row] = bk;
            }
        }
    }
    __syncthreads();
    if (tid < BM) {
        float bv = wmin[0][tid]; int bk = widx[0][tid];
        #pragma unroll
        for (int q = 1; q < 4; ++q) {
            float ov = wmin[q][tid]; int ok = widx[q][tid];
            if (ov < bv || (ov == bv && ok < bk)) { bv = ov; bk = ok; }
        }
        sidx[tid] = bk;
    }
    __syncthreads();

    // ---- epilogue: gather code row, write q, residual, loss ----
    const int lrow = tid >> 2;
    const int kidx = sidx[lrow];
    const long grow = row0 + lrow;
    const float* cbr = cb + (size_t)kidx * DIM;
    float* qr = qout + grow * 1024;
    float* rr = resout ? resout + grow * 1024 : nullptr;
    float lsq = 0.f;
    #pragma unroll
    for (int e = 0; e < 8; ++e) {
        int k8 = (tid & 3) + 4 * e;
        int off = ((lrow << 9) + (k8 << 4)) ^ ((lrow & 7) << 4);
        bf16x8 h = *(const bf16x8*)(Ahi + off);
        bf16x8 l = *(const bf16x8*)(Alo + off);
        float4 c0 = *(const float4*)(cbr + k8 * 8);
        float4 c1 = *(const float4*)(cbr + k8 * 8 + 4);
        float cs[8] = {c0.x, c0.y, c0.z, c0.w, c1.x, c1.y, c1.z, c1.w};
        float qv[8], rv[8];
        #pragma unroll
        for (int i = 0; i < 8; ++i) {
            float x = bf2f((unsigned short)h[i]) + bf2f((unsigned short)l[i]);
            qv[i] = x + (cs[i] - x);
            rv[i] = x - qv[i];
            lsq += rv[i] * rv[i];
        }
        *(float4*)(qr + k8 * 8)     = (float4){qv[0], qv[1], qv[2], qv[3]};
        *(float4*)(qr + k8 * 8 + 4) = (float4){qv[4], qv[5], qv[6], qv[7]};
        if (rr) {
            *(float4*)(rr + k8 * 8)     = (float4){rv[0], rv[1], rv[2], rv[3]};
            *(float4*)(rr + k8 * 8 + 4) = (float4){rv[4], rv[5], rv[6], rv[7]};
        }
    }
    #pragma unroll
    for (int off = 32; off; off >>= 1) lsq += __shfl_down(lsq, off);
    if ((tid & 63) == 0) red[tid >> 6] = lsq;
    __syncthreads();
    if (tid == 0) sq_partials[blockIdx.x] = red[0] + red[1] + red[2] + red[3];

    if (tid < BM) atomicAdd(&hist[sidx[tid]], 1);
    if (emap && tid < BM) logits[row0 + tid] = (float)emap[sidx[tid]];
}

// ---------------- finalize: loss + perplexities ----------------
__global__ void finalize_kernel(const float* __restrict__ sq_partials,
                                const int* __restrict__ hist,
                                float* __restrict__ loss_out,
                                float* __restrict__ perp_out)
{
    __shared__ float sred[8];
    int tid = threadIdx.x;  // 512
    float s = 0.f;
    for (int i = tid; i < NUM_VQ * NBLOCKS; i += 512) s += sq_partials[i];
    #pragma unroll
    for (int off = 32; off; off >>= 1) s += __shfl_down(s, off);
    if ((tid & 63) == 0) sred[tid >> 6] = s;
    __syncthreads();
    if (tid == 0) {
        float t = 0.f;
        for (int i = 0; i < 8; ++i) t += sred[i];
        *loss_out = (1.f + BETA) * t / ((float)N_VEC * (float)DIM);
    }
    for (int st = 0; st < NUM_VQ; ++st) {
        __syncthreads();
        float e = (float)hist[st * 512 + tid] * (1.f / (float)N_VEC);
        float term = e * logf(e + 1e-10f);
        #pragma unroll
        for (int off = 32; off; off >>= 1) term += __shfl_down(term, off);
        if ((tid & 63) == 0) sred[tid >> 6] = term;
        __syncthreads();
        if (tid == 0) {
            float t = 0.f;
            for (int i = 0; i < 8; ++i) t += sred[i];
            perp_out[st] = expf(-t);
        }
    }
}

extern "C" void kernel_launch(void* const* d_in, const int* in_sizes, int n_in,
                              void* d_out, int out_size, void* d_ws, size_t ws_size,
                              hipStream_t stream) {
    const float* x    = (const float*)d_in[0];
    const float* cbs  = (const float*)d_in[1];
    const int*   emap = (const int*)d_in[2];
    float* out = (float*)d_out;

    const size_t QSZ = (size_t)N_VEC * (NUM_VQ * DIM);
    float* loss_out = out + QSZ;
    float* logits   = out + QSZ + 1;
    float* perp     = out + QSZ + 1 + N_VEC;

    // ws: sq_partials[4*2048] f32 | hist[4*512] i32 | norms[2048] f32 | B' 2MB
    float* sq_partials = (float*)d_ws;
    int*   hist        = (int*)(sq_partials + NUM_VQ * NBLOCKS);
    float* norms       = (float*)(hist + NUM_VQ * KCODES);
    char*  bprep       = (char*)(norms + NUM_VQ * KCODES);

    hipMemsetAsync(d_ws, 0, (size_t)(NUM_VQ * NBLOCKS + NUM_VQ * KCODES) * 4, stream);

    norms_kernel<<<NUM_VQ * KCODES / 4, 256, 0, stream>>>(cbs, norms);
    bprep_kernel<<<512, 256, 0, stream>>>(cbs, bprep);

    float* resid = out + 3 * DIM;   // fp32 residual in stage-3 output column

    for (int s = 0; s < NUM_VQ; ++s) {
        const float* xin = (s == 0) ? x : resid;
        int xstride      = (s == 0) ? DIM : 1024;
        float* qout      = out + s * DIM;
        float* resout    = (s == NUM_VQ - 1) ? nullptr : resid;
        vq_stage_mfma<<<NBLOCKS, NTHREADS, 0, stream>>>(
            xin, xstride,
            bprep + (size_t)s * 16 * 32768,
            cbs + (size_t)s * KCODES * DIM,
            norms + s * KCODES,
            qout, resout,
            sq_partials + s * NBLOCKS,
            hist + s * KCODES,
            (s == 0) ? emap : nullptr,
            (s == 0) ? logits : nullptr);
    }
    finalize_kernel<<<1, 512, 0, stream>>>(sq_partials, hist, loss_out, perp);
}

// Round 3
// 837.052 us; speedup vs baseline: 5.5400x; 1.3973x over previous
//
#include <hip/hip_runtime.h>

#define N_VEC 131072
#define DIM 256
#define KCODES 512
#define NUM_VQ 4

constexpr float BETA = 0.2f;
constexpr int BM = 64;
constexpr int NTHREADS = 256;
constexpr int NBLOCKS = N_VEC / BM;   // 2048

typedef short bf16x8 __attribute__((ext_vector_type(8)));
typedef float f32x4  __attribute__((ext_vector_type(4)));

__device__ __forceinline__ unsigned short f2bf(float x) {
    unsigned u = __builtin_bit_cast(unsigned, x);
    u += 0x7FFF + ((u >> 16) & 1);          // round-to-nearest-even
    return (unsigned short)(u >> 16);
}
__device__ __forceinline__ float bf2f(unsigned short h) {
    unsigned u = ((unsigned)h) << 16;
    return __builtin_bit_cast(float, u);
}

// ---------------- codebook norms (exact fp32) ----------------
__global__ void norms_kernel(const float* __restrict__ cb, float* __restrict__ norms) {
    int row = blockIdx.x * 4 + (threadIdx.x >> 6);
    int lane = threadIdx.x & 63;
    const float* r = cb + (size_t)row * DIM;
    float4 v = *(const float4*)(r + lane * 4);
    float s = v.x * v.x + v.y * v.y + v.z * v.z + v.w * v.w;
    #pragma unroll
    for (int off = 32; off; off >>= 1) s += __shfl_down(s, off);
    if (lane == 0) norms[row] = s;
}

// ---------------- codebook -> fragment-granule bf16 hi/lo image ----------------
// B'[stage][plane][ks][ct][lane] : 16B granule = 8 bf16 of
//   col = ct*16 + (lane&15),  k = ks*32 + (lane>>4)*8 .. +8
// so one coalesced global_load_dwordx4 per lane IS one MFMA B-fragment.
__global__ void bprep_kernel(const float* __restrict__ cb, char* __restrict__ bp) {
    int id = blockIdx.x * 256 + threadIdx.x;   // 131072 total
    int lane = id & 63;
    int ct   = (id >> 6) & 31;
    int ks   = (id >> 11) & 7;
    int p    = (id >> 14) & 1;
    int s    = id >> 15;
    int col  = ct * 16 + (lane & 15);
    int kb   = ks * 32 + (lane >> 4) * 8;
    const float* src = cb + ((size_t)(s * KCODES + col)) * DIM + kb;
    float4 v0 = *(const float4*)src;
    float4 v1 = *(const float4*)(src + 4);
    float xs[8] = {v0.x, v0.y, v0.z, v0.w, v1.x, v1.y, v1.z, v1.w};
    bf16x8 o;
    #pragma unroll
    for (int i = 0; i < 8; ++i) {
        unsigned short hi = f2bf(xs[i]);
        o[i] = (short)(p ? f2bf(xs[i] - bf2f(hi)) : hi);
    }
    size_t off = ((((size_t)s * 2 + p) * 8 + ks) * 32 + ct) * 1024 + (size_t)lane * 16;
    *(bf16x8*)(bp + off) = o;
}

// ---------------- one residual-VQ stage (MFMA, barrier-free K-loop) ----------------
__global__ __launch_bounds__(NTHREADS, 2)
void vq_stage_mfma(const float* xin, int xin_stride,
                   const char* __restrict__ bp,     // this stage's B' (512KB)
                   const float* __restrict__ cb,    // fp32 codebook this stage
                   const float* __restrict__ norms, // [512]
                   float* qout, float* resout,
                   float* __restrict__ sq_partials,
                   int* __restrict__ hist,
                   const int* __restrict__ emap,
                   float* __restrict__ logits)
{
    __shared__ __align__(16) char Ahi[32768];
    __shared__ __align__(16) char Alo[32768];
    __shared__ float ns[KCODES];
    __shared__ float wmin[4][BM];
    __shared__ int   widx[4][BM];
    __shared__ int   sidx[BM];
    __shared__ float red[4];

    const int tid  = threadIdx.x;
    const int w    = tid >> 6;
    const int lane = tid & 63;
    const int l15  = lane & 15;
    const int h16  = lane >> 4;        // 0..3
    const long row0 = (long)blockIdx.x * BM;

    // ---- stage A: 64x256 fp32 -> hi/lo bf16, XOR-swizzled ----
    #pragma unroll
    for (int e = 0; e < 8; ++e) {
        int ga = e * 256 + tid;
        int row = ga >> 5, k8 = ga & 31;
        const float* src = xin + (row0 + row) * (long)xin_stride + k8 * 8;
        float4 v0 = *(const float4*)src;
        float4 v1 = *(const float4*)(src + 4);
        float xs[8] = {v0.x, v0.y, v0.z, v0.w, v1.x, v1.y, v1.z, v1.w};
        bf16x8 h, l;
        #pragma unroll
        for (int i = 0; i < 8; ++i) {
            unsigned short hb = f2bf(xs[i]);
            h[i] = (short)hb;
            l[i] = (short)f2bf(xs[i] - bf2f(hb));
        }
        int off = ((row << 9) + (k8 << 4)) ^ ((row & 7) << 4);
        *(bf16x8*)(Ahi + off) = h;
        *(bf16x8*)(Alo + off) = l;
    }
    ns[tid]       = norms[tid];
    ns[tid + 256] = norms[tid + 256];
    __syncthreads();

    f32x4 acc[4][8];
    #pragma unroll
    for (int t = 0; t < 4; ++t)
        #pragma unroll
        for (int c = 0; c < 8; ++c)
            acc[t][c] = (f32x4){0.f, 0.f, 0.f, 0.f};

    // wave w owns cols [w*128, w*128+128); B-fragment base for ct = w*8
    const char* bw = bp + (size_t)w * 8192 + (size_t)lane * 16;
    // addr(plane, ks, c) = bw + plane*262144 + ks*32768 + c*1024

    #pragma unroll
    for (int ks = 0; ks < 8; ++ks) {
        bf16x8 ah[4], al[4];
        #pragma unroll
        for (int t = 0; t < 4; ++t) {
            int row = t * 16 + l15;
            int k8  = ks * 4 + h16;
            int off = ((row << 9) + (k8 << 4)) ^ ((row & 7) << 4);
            ah[t] = *(const bf16x8*)(Ahi + off);
            al[t] = *(const bf16x8*)(Alo + off);
        }
        #pragma unroll
        for (int half = 0; half < 2; ++half) {
            bf16x8 bh[4], bl[4];
            #pragma unroll
            for (int c = 0; c < 4; ++c) {
                const char* q = bw + (size_t)ks * 32768 + (size_t)(half * 4 + c) * 1024;
                bh[c] = *(const bf16x8*)(q);
                bl[c] = *(const bf16x8*)(q + 262144);
            }
            #pragma unroll
            for (int c = 0; c < 4; ++c) {
                int cc = half * 4 + c;
                #pragma unroll
                for (int t = 0; t < 4; ++t) {
                    acc[t][cc] = __builtin_amdgcn_mfma_f32_16x16x32_bf16(ah[t], bh[c], acc[t][cc], 0, 0, 0);
                    acc[t][cc] = __builtin_amdgcn_mfma_f32_16x16x32_bf16(al[t], bh[c], acc[t][cc], 0, 0, 0);
                    acc[t][cc] = __builtin_amdgcn_mfma_f32_16x16x32_bf16(ah[t], bl[c], acc[t][cc], 0, 0, 0);
                }
            }
        }
    }

    // ---- argmin: scores s = ||c||^2 - 2*dot ----
    #pragma unroll
    for (int t = 0; t < 4; ++t) {
        #pragma unroll
        for (int r = 0; r < 4; ++r) {
            float bv = 3.4e38f; int bk = 0;
            #pragma unroll
            for (int c = 0; c < 8; ++c) {
                int col = w * 128 + c * 16 + l15;
                float s = ns[col] - 2.0f * acc[t][c][r];
                if (s < bv || (s == bv && col < bk)) { bv = s; bk = col; }
            }
            #pragma unroll
            for (int m = 1; m < 16; m <<= 1) {
                float ov = __shfl_xor(bv, m);
                int   ok = __shfl_xor(bk, m);
                if (ov < bv || (ov == bv && ok < bk)) { bv = ov; bk = ok; }
            }
            if (l15 == 0) {
                int row = t * 16 + h16 * 4 + r;
                wmin[w][row] = bv; widx[w][row] = bk;
            }
        }
    }
    __syncthreads();
    if (tid < BM) {
        float bv = wmin[0][tid]; int bk = widx[0][tid];
        #pragma unroll
        for (int q2 = 1; q2 < 4; ++q2) {
            float ov = wmin[q2][tid]; int ok = widx[q2][tid];
            if (ov < bv || (ov == bv && ok < bk)) { bv = ov; bk = ok; }
        }
        sidx[tid] = bk;
    }
    __syncthreads();

    // ---- epilogue: gather code row, write q, residual, loss ----
    const int lrow = tid >> 2;
    const int kidx = sidx[lrow];
    const long grow = row0 + lrow;
    const float* cbr = cb + (size_t)kidx * DIM;
    float* qr = qout + grow * 1024;
    float* rr = resout ? resout + grow * 1024 : nullptr;
    float lsq = 0.f;
    #pragma unroll
    for (int e = 0; e < 8; ++e) {
        int k8 = (tid & 3) + 4 * e;
        int off = ((lrow << 9) + (k8 << 4)) ^ ((lrow & 7) << 4);
        bf16x8 h = *(const bf16x8*)(Ahi + off);
        bf16x8 l = *(const bf16x8*)(Alo + off);
        float4 c0 = *(const float4*)(cbr + k8 * 8);
        float4 c1 = *(const float4*)(cbr + k8 * 8 + 4);
        float cs[8] = {c0.x, c0.y, c0.z, c0.w, c1.x, c1.y, c1.z, c1.w};
        float qv[8], rv[8];
        #pragma unroll
        for (int i = 0; i < 8; ++i) {
            float x = bf2f((unsigned short)h[i]) + bf2f((unsigned short)l[i]);
            qv[i] = x + (cs[i] - x);
            rv[i] = x - qv[i];
            lsq += rv[i] * rv[i];
        }
        *(float4*)(qr + k8 * 8)     = (float4){qv[0], qv[1], qv[2], qv[3]};
        *(float4*)(qr + k8 * 8 + 4) = (float4){qv[4], qv[5], qv[6], qv[7]};
        if (rr) {
            *(float4*)(rr + k8 * 8)     = (float4){rv[0], rv[1], rv[2], rv[3]};
            *(float4*)(rr + k8 * 8 + 4) = (float4){rv[4], rv[5], rv[6], rv[7]};
        }
    }
    #pragma unroll
    for (int off = 32; off; off >>= 1) lsq += __shfl_down(lsq, off);
    if ((tid & 63) == 0) red[tid >> 6] = lsq;
    __syncthreads();
    if (tid == 0) sq_partials[blockIdx.x] = red[0] + red[1] + red[2] + red[3];

    if (tid < BM) atomicAdd(&hist[sidx[tid]], 1);
    if (emap && tid < BM) logits[row0 + tid] = (float)emap[sidx[tid]];
}

// ---------------- finalize: loss + perplexities ----------------
__global__ void finalize_kernel(const float* __restrict__ sq_partials,
                                const int* __restrict__ hist,
                                float* __restrict__ loss_out,
                                float* __restrict__ perp_out)
{
    __shared__ float sred[8];
    int tid = threadIdx.x;  // 512
    float s = 0.f;
    for (int i = tid; i < NUM_VQ * NBLOCKS; i += 512) s += sq_partials[i];
    #pragma unroll
    for (int off = 32; off; off >>= 1) s += __shfl_down(s, off);
    if ((tid & 63) == 0) sred[tid >> 6] = s;
    __syncthreads();
    if (tid == 0) {
        float t = 0.f;
        for (int i = 0; i < 8; ++i) t += sred[i];
        *loss_out = (1.f + BETA) * t / ((float)N_VEC * (float)DIM);
    }
    for (int st = 0; st < NUM_VQ; ++st) {
        __syncthreads();
        float e = (float)hist[st * 512 + tid] * (1.f / (float)N_VEC);
        float term = e * logf(e + 1e-10f);
        #pragma unroll
        for (int off = 32; off; off >>= 1) term += __shfl_down(term, off);
        if ((tid & 63) == 0) sred[tid >> 6] = term;
        __syncthreads();
        if (tid == 0) {
            float t = 0.f;
            for (int i = 0; i < 8; ++i) t += sred[i];
            perp_out[st] = expf(-t);
        }
    }
}

extern "C" void kernel_launch(void* const* d_in, const int* in_sizes, int n_in,
                              void* d_out, int out_size, void* d_ws, size_t ws_size,
                              hipStream_t stream) {
    const float* x    = (const float*)d_in[0];
    const float* cbs  = (const float*)d_in[1];
    const int*   emap = (const int*)d_in[2];
    float* out = (float*)d_out;

    const size_t QSZ = (size_t)N_VEC * (NUM_VQ * DIM);
    float* loss_out = out + QSZ;
    float* logits   = out + QSZ + 1;
    float* perp     = out + QSZ + 1 + N_VEC;

    // ws: sq_partials[4*2048] f32 | hist[4*512] i32 | norms[2048] f32 | B' 2MB
    float* sq_partials = (float*)d_ws;
    int*   hist        = (int*)(sq_partials + NUM_VQ * NBLOCKS);
    float* norms       = (float*)(hist + NUM_VQ * KCODES);
    char*  bprep       = (char*)(norms + NUM_VQ * KCODES);

    hipMemsetAsync(d_ws, 0, (size_t)(NUM_VQ * NBLOCKS + NUM_VQ * KCODES) * 4, stream);

    norms_kernel<<<NUM_VQ * KCODES / 4, 256, 0, stream>>>(cbs, norms);
    bprep_kernel<<<512, 256, 0, stream>>>(cbs, bprep);

    float* resid = out + 3 * DIM;   // fp32 residual in stage-3 output column

    for (int s = 0; s < NUM_VQ; ++s) {
        const float* xin = (s == 0) ? x : resid;
        int xstride      = (s == 0) ? DIM : 1024;
        float* qout      = out + s * DIM;
        float* resout    = (s == NUM_VQ - 1) ? nullptr : resid;
        vq_stage_mfma<<<NBLOCKS, NTHREADS, 0, stream>>>(
            xin, xstride,
            bprep + (size_t)s * 524288,
            cbs + (size_t)s * KCODES * DIM,
            norms + s * KCODES,
            qout, resout,
            sq_partials + s * NBLOCKS,
            hist + s * KCODES,
            (s == 0) ? emap : nullptr,
            (s == 0) ? logits : nullptr);
    }
    finalize_kernel<<<1, 512, 0, stream>>>(sq_partials, hist, loss_out, perp);
}

// Round 4
// 798.090 us; speedup vs baseline: 5.8105x; 1.0488x over previous
//
#include <hip/hip_runtime.h>

#define N_VEC 131072
#define DIM 256
#define KCODES 512
#define NUM_VQ 4

constexpr float BETA = 0.2f;
constexpr int BM = 64;
constexpr int NTHREADS = 256;
constexpr int NBLOCKS = N_VEC / BM;   // 2048

typedef short bf16x8 __attribute__((ext_vector_type(8)));
typedef float f32x4  __attribute__((ext_vector_type(4)));

__device__ __forceinline__ unsigned short f2bf(float x) {
    unsigned u = __builtin_bit_cast(unsigned, x);
    u += 0x7FFF + ((u >> 16) & 1);          // round-to-nearest-even
    return (unsigned short)(u >> 16);
}
__device__ __forceinline__ float bf2f(unsigned short h) {
    unsigned u = ((unsigned)h) << 16;
    return __builtin_bit_cast(float, u);
}

// ---------------- codebook norms (exact fp32) + hist zeroing ----------------
__global__ void norms_kernel(const float* __restrict__ cb, float* __restrict__ norms,
                             int* __restrict__ hist) {
    if (blockIdx.x < 8) hist[blockIdx.x * 256 + threadIdx.x] = 0;
    int row = blockIdx.x * 4 + (threadIdx.x >> 6);
    int lane = threadIdx.x & 63;
    const float* r = cb + (size_t)row * DIM;
    float4 v = *(const float4*)(r + lane * 4);
    float s = v.x * v.x + v.y * v.y + v.z * v.z + v.w * v.w;
    #pragma unroll
    for (int off = 32; off; off >>= 1) s += __shfl_down(s, off);
    if (lane == 0) norms[row] = s;
}

// ---------------- codebook -> fragment-granule bf16 hi/lo image ----------------
// B'[stage][plane][ks][ct][lane] : 16B granule = 8 bf16 of
//   col = ct*16 + (lane&15),  k = ks*32 + (lane>>4)*8 .. +8
__global__ void bprep_kernel(const float* __restrict__ cb, char* __restrict__ bp) {
    int id = blockIdx.x * 256 + threadIdx.x;   // 131072 total
    int lane = id & 63;
    int ct   = (id >> 6) & 31;
    int ks   = (id >> 11) & 7;
    int p    = (id >> 14) & 1;
    int s    = id >> 15;
    int col  = ct * 16 + (lane & 15);
    int kb   = ks * 32 + (lane >> 4) * 8;
    const float* src = cb + ((size_t)(s * KCODES + col)) * DIM + kb;
    float4 v0 = *(const float4*)src;
    float4 v1 = *(const float4*)(src + 4);
    float xs[8] = {v0.x, v0.y, v0.z, v0.w, v1.x, v1.y, v1.z, v1.w};
    bf16x8 o;
    #pragma unroll
    for (int i = 0; i < 8; ++i) {
        unsigned short hi = f2bf(xs[i]);
        o[i] = (short)(p ? f2bf(xs[i] - bf2f(hi)) : hi);
    }
    size_t off = ((((size_t)s * 2 + p) * 8 + ks) * 32 + ct) * 1024 + (size_t)lane * 16;
    *(bf16x8*)(bp + off) = o;
}

// ---------------- fused 4-stage residual VQ ----------------
__global__ __launch_bounds__(NTHREADS, 2)
void vq_fused(const float* __restrict__ x,
              const char* __restrict__ bp,     // B' all stages (2MB)
              const float* __restrict__ cb,    // fp32 codebooks [4][512][256]
              const float* __restrict__ norms, // [4][512]
              float* __restrict__ out,         // q base, row stride 1024
              float* __restrict__ sq_partials, // [4][2048]
              int* __restrict__ hist,          // [4][512]
              const int* __restrict__ emap,
              float* __restrict__ logits)
{
    __shared__ __align__(16) char Ahi[32768];
    __shared__ __align__(16) char Alo[32768];
    __shared__ float ns[KCODES];
    __shared__ float wmin[4][BM];
    __shared__ int   widx[4][BM];
    __shared__ int   sidx[BM];
    __shared__ float red[4];

    const int tid  = threadIdx.x;
    const int w    = tid >> 6;
    const int lane = tid & 63;
    const int l15  = lane & 15;
    const int h16  = lane >> 4;        // 0..3
    const long row0 = (long)blockIdx.x * BM;

    // ---- stage A once: 64x256 fp32 -> hi/lo bf16, XOR-swizzled ----
    #pragma unroll
    for (int e = 0; e < 8; ++e) {
        int ga = e * 256 + tid;
        int row = ga >> 5, k8 = ga & 31;
        const float* src = x + (row0 + row) * (long)DIM + k8 * 8;
        float4 v0 = *(const float4*)src;
        float4 v1 = *(const float4*)(src + 4);
        float xs[8] = {v0.x, v0.y, v0.z, v0.w, v1.x, v1.y, v1.z, v1.w};
        bf16x8 h, l;
        #pragma unroll
        for (int i = 0; i < 8; ++i) {
            unsigned short hb = f2bf(xs[i]);
            h[i] = (short)hb;
            l[i] = (short)f2bf(xs[i] - bf2f(hb));
        }
        int off = ((row << 9) + (k8 << 4)) ^ ((row & 7) << 4);
        *(bf16x8*)(Ahi + off) = h;
        *(bf16x8*)(Alo + off) = l;
    }

    #pragma unroll 1
    for (int s = 0; s < NUM_VQ; ++s) {
        ns[tid]       = norms[s * KCODES + tid];
        ns[tid + 256] = norms[s * KCODES + tid + 256];
        __syncthreads();   // A plane + ns ready

        f32x4 acc[4][8];
        #pragma unroll
        for (int t = 0; t < 4; ++t)
            #pragma unroll
            for (int c = 0; c < 8; ++c)
                acc[t][c] = (f32x4){0.f, 0.f, 0.f, 0.f};

        const char* bw = bp + (size_t)s * 524288 + (size_t)w * 8192 + (size_t)lane * 16;

        #pragma unroll
        for (int ks = 0; ks < 8; ++ks) {
            bf16x8 ah[4], al[4];
            #pragma unroll
            for (int t = 0; t < 4; ++t) {
                int row = t * 16 + l15;
                int k8  = ks * 4 + h16;
                int off = ((row << 9) + (k8 << 4)) ^ ((row & 7) << 4);
                ah[t] = *(const bf16x8*)(Ahi + off);
                al[t] = *(const bf16x8*)(Alo + off);
            }
            #pragma unroll
            for (int half = 0; half < 2; ++half) {
                bf16x8 bh[4], bl[4];
                #pragma unroll
                for (int c = 0; c < 4; ++c) {
                    const char* q = bw + (size_t)ks * 32768 + (size_t)(half * 4 + c) * 1024;
                    bh[c] = *(const bf16x8*)(q);
                    bl[c] = *(const bf16x8*)(q + 262144);
                }
                #pragma unroll
                for (int c = 0; c < 4; ++c) {
                    int cc = half * 4 + c;
                    #pragma unroll
                    for (int t = 0; t < 4; ++t) {
                        acc[t][cc] = __builtin_amdgcn_mfma_f32_16x16x32_bf16(ah[t], bh[c], acc[t][cc], 0, 0, 0);
                        acc[t][cc] = __builtin_amdgcn_mfma_f32_16x16x32_bf16(al[t], bh[c], acc[t][cc], 0, 0, 0);
                        acc[t][cc] = __builtin_amdgcn_mfma_f32_16x16x32_bf16(ah[t], bl[c], acc[t][cc], 0, 0, 0);
                    }
                }
            }
        }

        // ---- argmin: scores = ||c||^2 - 2*dot ----
        #pragma unroll
        for (int t = 0; t < 4; ++t) {
            #pragma unroll
            for (int r = 0; r < 4; ++r) {
                float bv = 3.4e38f; int bk = 0;
                #pragma unroll
                for (int c = 0; c < 8; ++c) {
                    int col = w * 128 + c * 16 + l15;
                    float sc = ns[col] - 2.0f * acc[t][c][r];
                    if (sc < bv || (sc == bv && col < bk)) { bv = sc; bk = col; }
                }
                #pragma unroll
                for (int m = 1; m < 16; m <<= 1) {
                    float ov = __shfl_xor(bv, m);
                    int   ok = __shfl_xor(bk, m);
                    if (ov < bv || (ov == bv && ok < bk)) { bv = ov; bk = ok; }
                }
                if (l15 == 0) {
                    int row = t * 16 + h16 * 4 + r;
                    wmin[w][row] = bv; widx[w][row] = bk;
                }
            }
        }
        __syncthreads();
        if (tid < BM) {
            float bv = wmin[0][tid]; int bk = widx[0][tid];
            #pragma unroll
            for (int q2 = 1; q2 < 4; ++q2) {
                float ov = wmin[q2][tid]; int ok = widx[q2][tid];
                if (ov < bv || (ov == bv && ok < bk)) { bv = ov; bk = ok; }
            }
            sidx[tid] = bk;
        }
        __syncthreads();

        // ---- epilogue: gather code row, write q, update LDS residual, loss ----
        const int lrow = tid >> 2;
        const int kidx = sidx[lrow];
        const long grow = row0 + lrow;
        const float* cbr = cb + ((size_t)s * KCODES + kidx) * DIM;
        float* qr = out + grow * 1024 + s * DIM;
        float lsq = 0.f;
        #pragma unroll
        for (int e = 0; e < 8; ++e) {
            int k8 = (tid & 3) + 4 * e;
            int off = ((lrow << 9) + (k8 << 4)) ^ ((lrow & 7) << 4);
            bf16x8 h = *(const bf16x8*)(Ahi + off);
            bf16x8 l = *(const bf16x8*)(Alo + off);
            float4 c0 = *(const float4*)(cbr + k8 * 8);
            float4 c1 = *(const float4*)(cbr + k8 * 8 + 4);
            float cs[8] = {c0.x, c0.y, c0.z, c0.w, c1.x, c1.y, c1.z, c1.w};
            float qv[8], rv[8];
            #pragma unroll
            for (int i = 0; i < 8; ++i) {
                float xv = bf2f((unsigned short)h[i]) + bf2f((unsigned short)l[i]);
                qv[i] = xv + (cs[i] - xv);
                rv[i] = xv - qv[i];
                lsq += rv[i] * rv[i];
            }
            *(float4*)(qr + k8 * 8)     = (float4){qv[0], qv[1], qv[2], qv[3]};
            *(float4*)(qr + k8 * 8 + 4) = (float4){qv[4], qv[5], qv[6], qv[7]};
            if (s < NUM_VQ - 1) {
                bf16x8 nh, nl;
                #pragma unroll
                for (int i = 0; i < 8; ++i) {
                    unsigned short hb = f2bf(rv[i]);
                    nh[i] = (short)hb;
                    nl[i] = (short)f2bf(rv[i] - bf2f(hb));
                }
                *(bf16x8*)(Ahi + off) = nh;
                *(bf16x8*)(Alo + off) = nl;
            }
        }
        #pragma unroll
        for (int off = 32; off; off >>= 1) lsq += __shfl_down(lsq, off);
        if ((tid & 63) == 0) red[tid >> 6] = lsq;
        __syncthreads();
        if (tid == 0) sq_partials[s * NBLOCKS + blockIdx.x] = red[0] + red[1] + red[2] + red[3];

        if (tid < BM) atomicAdd(&hist[s * KCODES + sidx[tid]], 1);
        if (s == 0 && tid < BM) logits[row0 + tid] = (float)emap[sidx[tid]];
    }
}

// ---------------- finalize: loss + perplexities ----------------
__global__ void finalize_kernel(const float* __restrict__ sq_partials,
                                const int* __restrict__ hist,
                                float* __restrict__ loss_out,
                                float* __restrict__ perp_out)
{
    __shared__ float sred[8];
    int tid = threadIdx.x;  // 512
    float s = 0.f;
    for (int i = tid; i < NUM_VQ * NBLOCKS; i += 512) s += sq_partials[i];
    #pragma unroll
    for (int off = 32; off; off >>= 1) s += __shfl_down(s, off);
    if ((tid & 63) == 0) sred[tid >> 6] = s;
    __syncthreads();
    if (tid == 0) {
        float t = 0.f;
        for (int i = 0; i < 8; ++i) t += sred[i];
        *loss_out = (1.f + BETA) * t / ((float)N_VEC * (float)DIM);
    }
    for (int st = 0; st < NUM_VQ; ++st) {
        __syncthreads();
        float e = (float)hist[st * 512 + tid] * (1.f / (float)N_VEC);
        float term = e * logf(e + 1e-10f);
        #pragma unroll
        for (int off = 32; off; off >>= 1) term += __shfl_down(term, off);
        if ((tid & 63) == 0) sred[tid >> 6] = term;
        __syncthreads();
        if (tid == 0) {
            float t = 0.f;
            for (int i = 0; i < 8; ++i) t += sred[i];
            perp_out[st] = expf(-t);
        }
    }
}

extern "C" void kernel_launch(void* const* d_in, const int* in_sizes, int n_in,
                              void* d_out, int out_size, void* d_ws, size_t ws_size,
                              hipStream_t stream) {
    const float* x    = (const float*)d_in[0];
    const float* cbs  = (const float*)d_in[1];
    const int*   emap = (const int*)d_in[2];
    float* out = (float*)d_out;

    const size_t QSZ = (size_t)N_VEC * (NUM_VQ * DIM);
    float* loss_out = out + QSZ;
    float* logits   = out + QSZ + 1;
    float* perp     = out + QSZ + 1 + N_VEC;

    // ws: sq_partials[4*2048] f32 | hist[4*512] i32 | norms[2048] f32 | B' 2MB
    float* sq_partials = (float*)d_ws;
    int*   hist        = (int*)(sq_partials + NUM_VQ * NBLOCKS);
    float* norms       = (float*)(hist + NUM_VQ * KCODES);
    char*  bprep       = (char*)(norms + NUM_VQ * KCODES);

    norms_kernel<<<NUM_VQ * KCODES / 4, 256, 0, stream>>>(cbs, norms, hist);
    bprep_kernel<<<512, 256, 0, stream>>>(cbs, bprep);

    vq_fused<<<NBLOCKS, NTHREADS, 0, stream>>>(
        x, bprep, cbs, norms, out, sq_partials, hist, emap, logits);

    finalize_kernel<<<1, 512, 0, stream>>>(sq_partials, hist, loss_out, perp);
}

// Round 6
// 710.219 us; speedup vs baseline: 6.5294x; 1.1237x over previous
//
#include <hip/hip_runtime.h>

#define N_VEC 131072
#define DIM 256
#define KCODES 512
#define NUM_VQ 4

constexpr float BETA = 0.2f;
constexpr int BM = 64;
constexpr int NTHREADS = 256;
constexpr int NBLOCKS = N_VEC / BM;   // 2048

typedef short bf16x8 __attribute__((ext_vector_type(8)));
typedef float f32x4  __attribute__((ext_vector_type(4)));

__device__ __forceinline__ unsigned short f2bf(float x) {
    unsigned u = __builtin_bit_cast(unsigned, x);
    u += 0x7FFF + ((u >> 16) & 1);          // round-to-nearest-even
    return (unsigned short)(u >> 16);
}
__device__ __forceinline__ float bf2f(unsigned short h) {
    unsigned u = ((unsigned)h) << 16;
    return __builtin_bit_cast(float, u);
}

// ---------------- codebook norms (exact fp32) + hist zeroing ----------------
__global__ void norms_kernel(const float* __restrict__ cb, float* __restrict__ norms,
                             int* __restrict__ hist) {
    if (blockIdx.x < 8) hist[blockIdx.x * 256 + threadIdx.x] = 0;
    int row = blockIdx.x * 4 + (threadIdx.x >> 6);
    int lane = threadIdx.x & 63;
    const float* r = cb + (size_t)row * DIM;
    float4 v = *(const float4*)(r + lane * 4);
    float s = v.x * v.x + v.y * v.y + v.z * v.z + v.w * v.w;
    #pragma unroll
    for (int off = 32; off; off >>= 1) s += __shfl_down(s, off);
    if (lane == 0) norms[row] = s;
}

// ---------------- codebook -> fragment-granule bf16 hi/lo image ----------------
// B'[stage][plane][ks][ct][lane] : 16B granule = 8 bf16 of
//   col = ct*16 + (lane&15),  k = ks*32 + (lane>>4)*8 .. +8
__global__ void bprep_kernel(const float* __restrict__ cb, char* __restrict__ bp) {
    int id = blockIdx.x * 256 + threadIdx.x;   // 131072 total
    int lane = id & 63;
    int ct   = (id >> 6) & 31;
    int ks   = (id >> 11) & 7;
    int p    = (id >> 14) & 1;
    int s    = id >> 15;
    int col  = ct * 16 + (lane & 15);
    int kb   = ks * 32 + (lane >> 4) * 8;
    const float* src = cb + ((size_t)(s * KCODES + col)) * DIM + kb;
    float4 v0 = *(const float4*)src;
    float4 v1 = *(const float4*)(src + 4);
    float xs[8] = {v0.x, v0.y, v0.z, v0.w, v1.x, v1.y, v1.z, v1.w};
    bf16x8 o;
    #pragma unroll
    for (int i = 0; i < 8; ++i) {
        unsigned short hi = f2bf(xs[i]);
        o[i] = (short)(p ? f2bf(xs[i] - bf2f(hi)) : hi);
    }
    size_t off = ((((size_t)s * 2 + p) * 8 + ks) * 32 + ct) * 1024 + (size_t)lane * 16;
    *(bf16x8*)(bp + off) = o;
}

// ---------------- fused 4-stage residual VQ ----------------
__global__ __launch_bounds__(NTHREADS, 2)
void vq_fused(const float* __restrict__ x,
              const char* __restrict__ bp,     // B' all stages (2MB)
              const float* __restrict__ cb,    // fp32 codebooks [4][512][256]
              const float* __restrict__ norms, // [4][512]
              float* __restrict__ out,         // q base, row stride 1024
              float* __restrict__ sq_partials, // [2048*4] one per wave
              int* __restrict__ hist,          // [4][512]
              const int* __restrict__ emap,
              float* __restrict__ logits)
{
    __shared__ __align__(16) char Ahi[32768];
    __shared__ __align__(16) char Alo[32768];
    __shared__ float ns[KCODES];
    __shared__ float wmin[4][BM];
    __shared__ int   widx[4][BM];
    __shared__ int   sidx[BM];

    const int tid  = threadIdx.x;
    const int w    = tid >> 6;
    const int lane = tid & 63;
    const int l15  = lane & 15;
    const int h16  = lane >> 4;        // 0..3
    const long row0 = (long)blockIdx.x * BM;

    // ---- stage A once: 64x256 fp32 -> hi/lo bf16, XOR-swizzled (nt loads) ----
    #pragma unroll
    for (int e = 0; e < 8; ++e) {
        int ga = e * 256 + tid;
        int row = ga >> 5, k8 = ga & 31;
        const float* src = x + (row0 + row) * (long)DIM + k8 * 8;
        f32x4 v0 = __builtin_nontemporal_load((const f32x4*)src);
        f32x4 v1 = __builtin_nontemporal_load((const f32x4*)(src + 4));
        float xs[8] = {v0[0], v0[1], v0[2], v0[3], v1[0], v1[1], v1[2], v1[3]};
        bf16x8 h, l;
        #pragma unroll
        for (int i = 0; i < 8; ++i) {
            unsigned short hb = f2bf(xs[i]);
            h[i] = (short)hb;
            l[i] = (short)f2bf(xs[i] - bf2f(hb));
        }
        int off = ((row << 9) + (k8 << 4)) ^ ((row & 7) << 4);
        *(bf16x8*)(Ahi + off) = h;
        *(bf16x8*)(Alo + off) = l;
    }

    float lsq_acc = 0.f;   // loss partial, carried across stages (wave-reduced at end)

    #pragma unroll 1
    for (int s = 0; s < NUM_VQ; ++s) {
        ns[tid]       = norms[s * KCODES + tid];
        ns[tid + 256] = norms[s * KCODES + tid + 256];
        __syncthreads();   // A plane + ns ready

        f32x4 acc[4][8];
        #pragma unroll
        for (int t = 0; t < 4; ++t)
            #pragma unroll
            for (int c = 0; c < 8; ++c)
                acc[t][c] = (f32x4){0.f, 0.f, 0.f, 0.f};

        const char* bw = bp + (size_t)s * 524288 + (size_t)w * 8192 + (size_t)lane * 16;

        #pragma unroll
        for (int ks = 0; ks < 8; ++ks) {
            // issue ALL 16 B-fragment loads for this K-step first (wide load window)
            bf16x8 bh[8], bl[8];
            #pragma unroll
            for (int c = 0; c < 8; ++c) {
                const char* q = bw + (size_t)ks * 32768 + (size_t)c * 1024;
                bh[c] = *(const bf16x8*)(q);
                bl[c] = *(const bf16x8*)(q + 262144);
            }
            bf16x8 ah[4], al[4];
            #pragma unroll
            for (int t = 0; t < 4; ++t) {
                int row = t * 16 + l15;
                int k8  = ks * 4 + h16;
                int off = ((row << 9) + (k8 << 4)) ^ ((row & 7) << 4);
                ah[t] = *(const bf16x8*)(Ahi + off);
                al[t] = *(const bf16x8*)(Alo + off);
            }
            __builtin_amdgcn_s_setprio(1);
            #pragma unroll
            for (int c = 0; c < 8; ++c) {
                #pragma unroll
                for (int t = 0; t < 4; ++t) {
                    acc[t][c] = __builtin_amdgcn_mfma_f32_16x16x32_bf16(ah[t], bh[c], acc[t][c], 0, 0, 0);
                    acc[t][c] = __builtin_amdgcn_mfma_f32_16x16x32_bf16(al[t], bh[c], acc[t][c], 0, 0, 0);
                    acc[t][c] = __builtin_amdgcn_mfma_f32_16x16x32_bf16(ah[t], bl[c], acc[t][c], 0, 0, 0);
                }
            }
            __builtin_amdgcn_s_setprio(0);
        }

        // ---- argmin: scores = ||c||^2 - 2*dot ----
        #pragma unroll
        for (int t = 0; t < 4; ++t) {
            #pragma unroll
            for (int r = 0; r < 4; ++r) {
                float bv = 3.4e38f; int bk = 0;
                #pragma unroll
                for (int c = 0; c < 8; ++c) {
                    int col = w * 128 + c * 16 + l15;
                    float sc = ns[col] - 2.0f * acc[t][c][r];
                    if (sc < bv || (sc == bv && col < bk)) { bv = sc; bk = col; }
                }
                #pragma unroll
                for (int m = 1; m < 16; m <<= 1) {
                    float ov = __shfl_xor(bv, m);
                    int   ok = __shfl_xor(bk, m);
                    if (ov < bv || (ov == bv && ok < bk)) { bv = ov; bk = ok; }
                }
                if (l15 == 0) {
                    int row = t * 16 + h16 * 4 + r;
                    wmin[w][row] = bv; widx[w][row] = bk;
                }
            }
        }
        __syncthreads();
        if (tid < BM) {
            float bv = wmin[0][tid]; int bk = widx[0][tid];
            #pragma unroll
            for (int q2 = 1; q2 < 4; ++q2) {
                float ov = wmin[q2][tid]; int ok = widx[q2][tid];
                if (ov < bv || (ov == bv && ok < bk)) { bv = ov; bk = ok; }
            }
            sidx[tid] = bk;
        }
        __syncthreads();

        // ---- epilogue: gather code row, nt-write q, update LDS residual, loss ----
        const int lrow = tid >> 2;
        const int kidx = sidx[lrow];
        const long grow = row0 + lrow;
        const float* cbr = cb + ((size_t)s * KCODES + kidx) * DIM;
        float* qr = out + grow * 1024 + s * DIM;
        #pragma unroll
        for (int e = 0; e < 8; ++e) {
            int k8 = (tid & 3) + 4 * e;
            int off = ((lrow << 9) + (k8 << 4)) ^ ((lrow & 7) << 4);
            bf16x8 h = *(const bf16x8*)(Ahi + off);
            bf16x8 l = *(const bf16x8*)(Alo + off);
            float4 c0 = *(const float4*)(cbr + k8 * 8);
            float4 c1 = *(const float4*)(cbr + k8 * 8 + 4);
            float cs[8] = {c0.x, c0.y, c0.z, c0.w, c1.x, c1.y, c1.z, c1.w};
            float qv[8], rv[8];
            #pragma unroll
            for (int i = 0; i < 8; ++i) {
                float xv = bf2f((unsigned short)h[i]) + bf2f((unsigned short)l[i]);
                qv[i] = xv + (cs[i] - xv);
                rv[i] = xv - qv[i];
                lsq_acc += rv[i] * rv[i];
            }
            __builtin_nontemporal_store((f32x4){qv[0], qv[1], qv[2], qv[3]}, (f32x4*)(qr + k8 * 8));
            __builtin_nontemporal_store((f32x4){qv[4], qv[5], qv[6], qv[7]}, (f32x4*)(qr + k8 * 8 + 4));
            if (s < NUM_VQ - 1) {
                bf16x8 nh, nl;
                #pragma unroll
                for (int i = 0; i < 8; ++i) {
                    unsigned short hb = f2bf(rv[i]);
                    nh[i] = (short)hb;
                    nl[i] = (short)f2bf(rv[i] - bf2f(hb));
                }
                *(bf16x8*)(Ahi + off) = nh;
                *(bf16x8*)(Alo + off) = nl;
            }
        }

        if (tid < BM) atomicAdd(&hist[s * KCODES + sidx[tid]], 1);
        if (s == 0 && tid < BM) logits[row0 + tid] = (float)emap[sidx[tid]];
        // no barrier here: next stage's top barrier protects Ahi/Alo and ns
    }

    // wave-level loss partial (deterministic; one slot per wave)
    #pragma unroll
    for (int off = 32; off; off >>= 1) lsq_acc += __shfl_down(lsq_acc, off);
    if (lane == 0) sq_partials[blockIdx.x * 4 + w] = lsq_acc;
}

// ---------------- finalize: loss + perplexities ----------------
__global__ void finalize_kernel(const float* __restrict__ sq_partials,  // [8192]
                                const int* __restrict__ hist,
                                float* __restrict__ loss_out,
                                float* __restrict__ perp_out)
{
    __shared__ float sred[8];
    int tid = threadIdx.x;  // 512
    float s = 0.f;
    for (int i = tid; i < NBLOCKS * 4; i += 512) s += sq_partials[i];
    #pragma unroll
    for (int off = 32; off; off >>= 1) s += __shfl_down(s, off);
    if ((tid & 63) == 0) sred[tid >> 6] = s;
    __syncthreads();
    if (tid == 0) {
        float t = 0.f;
        for (int i = 0; i < 8; ++i) t += sred[i];
        *loss_out = (1.f + BETA) * t / ((float)N_VEC * (float)DIM);
    }
    for (int st = 0; st < NUM_VQ; ++st) {
        __syncthreads();
        float e = (float)hist[st * 512 + tid] * (1.f / (float)N_VEC);
        float term = e * logf(e + 1e-10f);
        #pragma unroll
        for (int off = 32; off; off >>= 1) term += __shfl_down(term, off);
        if ((tid & 63) == 0) sred[tid >> 6] = term;
        __syncthreads();
        if (tid == 0) {
            float t = 0.f;
            for (int i = 0; i < 8; ++i) t += sred[i];
            perp_out[st] = expf(-t);
        }
    }
}

extern "C" void kernel_launch(void* const* d_in, const int* in_sizes, int n_in,
                              void* d_out, int out_size, void* d_ws, size_t ws_size,
                              hipStream_t stream) {
    const float* x    = (const float*)d_in[0];
    const float* cbs  = (const float*)d_in[1];
    const int*   emap = (const int*)d_in[2];
    float* out = (float*)d_out;

    const size_t QSZ = (size_t)N_VEC * (NUM_VQ * DIM);
    float* loss_out = out + QSZ;
    float* logits   = out + QSZ + 1;
    float* perp     = out + QSZ + 1 + N_VEC;

    // ws: sq_partials[2048*4] f32 | hist[4*512] i32 | norms[2048] f32 | B' 2MB
    float* sq_partials = (float*)d_ws;
    int*   hist        = (int*)(sq_partials + NBLOCKS * 4);
    float* norms       = (float*)(hist + NUM_VQ * KCODES);
    char*  bprep       = (char*)(norms + NUM_VQ * KCODES);

    norms_kernel<<<NUM_VQ * KCODES / 4, 256, 0, stream>>>(cbs, norms, hist);
    bprep_kernel<<<512, 256, 0, stream>>>(cbs, bprep);

    vq_fused<<<NBLOCKS, NTHREADS, 0, stream>>>(
        x, bprep, cbs, norms, out, sq_partials, hist, emap, logits);

    finalize_kernel<<<1, 512, 0, stream>>>(sq_partials, hist, loss_out, perp);
}